// Round 1
// baseline (110.284 us; speedup 1.0000x reference)
//
#include <hip/hip_runtime.h>

// Corr1d_x_group: out[n, g*27+ch, h, w] =
//   0.25 * sum_{c<4} l[n, g*4+c, h, w] * r[n, g*4+c, h, w+ch-23]   (0 if w+ch-23 out of [0,W))
// N=8, Cin=16, H=256, W=512, G=4, TOP=27.  fp32 in/out.
// Memory-bound: 432 MiB out + 128 MiB in -> ~93us floor @ 6.3 TB/s.

#define TOP 27
#define GRP 4
#define CPG 4
#define HH 256
#define WW 512
#define NN 8
#define CIN 16

__global__ __launch_bounds__(256) void corr1d_kernel(
    const float* __restrict__ l, const float* __restrict__ r, float* __restrict__ out)
{
    const int t = threadIdx.x;           // 0..255, each thread owns w = 2t, 2t+1
    int b = blockIdx.x;                  // n*GRP*HH + g*HH + h
    const int h = b & (HH - 1);
    b >>= 8;
    const int g = b & (GRP - 1);
    const int n = b >> 2;

    // r row staged with zero halo: rsm[c][23 + w] = r[w]; [0..22] and [535..543] are zeros.
    __shared__ __align__(16) float rsm[CPG][WW + 32];

    const size_t HWs = (size_t)HH * WW;
    const float* lbase = l + (((size_t)n * CIN + (size_t)g * CPG) * HH + h) * WW;
    const float* rbase = r + (((size_t)n * CIN + (size_t)g * CPG) * HH + h) * WW;

    float2 lv[CPG];
#pragma unroll
    for (int c = 0; c < CPG; ++c) {
        lv[c] = *(const float2*)(lbase + c * HWs + 2 * t);
        float2 rv = *(const float2*)(rbase + c * HWs + 2 * t);
        rsm[c][23 + 2 * t]     = rv.x;
        rsm[c][23 + 2 * t + 1] = rv.y;
    }
    // zero the halos
    if (t < 23) {
#pragma unroll
        for (int c = 0; c < CPG; ++c) rsm[c][t] = 0.0f;
    } else if (t >= 256 - 9) {
        const int i = t - (256 - 9);     // 0..8 -> indices 535..543
#pragma unroll
        for (int c = 0; c < CPG; ++c) rsm[c][535 + i] = 0.0f;
    }
    __syncthreads();

    float acc0[TOP], acc1[TOP];
#pragma unroll
    for (int ch = 0; ch < TOP; ++ch) { acc0[ch] = 0.0f; acc1[ch] = 0.0f; }

#pragma unroll
    for (int c = 0; c < CPG; ++c) {
        // registers rv[j] = rsm[c][2t + j], j = 0..27  (14 x ds_read_b64, 8B-aligned)
        float rv[28];
#pragma unroll
        for (int k = 0; k < 14; ++k) {
            float2 v = *(const float2*)&rsm[c][2 * t + 2 * k];
            rv[2 * k]     = v.x;
            rv[2 * k + 1] = v.y;
        }
        const float a0 = lv[c].x, a1 = lv[c].y;
#pragma unroll
        for (int ch = 0; ch < TOP; ++ch) {
            acc0[ch] += a0 * rv[ch];
            acc1[ch] += a1 * rv[ch + 1];
        }
    }

    float* obase = out + (((size_t)n * (GRP * TOP) + (size_t)g * TOP) * HH + h) * WW + 2 * t;
#pragma unroll
    for (int ch = 0; ch < TOP; ++ch) {
        float2 o;
        o.x = acc0[ch] * 0.25f;
        o.y = acc1[ch] * 0.25f;
        *(float2*)(obase + ch * HWs) = o;
    }
}

extern "C" void kernel_launch(void* const* d_in, const int* in_sizes, int n_in,
                              void* d_out, int out_size, void* d_ws, size_t ws_size,
                              hipStream_t stream) {
    const float* l = (const float*)d_in[0];
    const float* r = (const float*)d_in[1];
    float* out = (float*)d_out;
    dim3 grid(NN * GRP * HH);   // 8192 blocks: one per (n, g, h) row
    corr1d_kernel<<<grid, 256, 0, stream>>>(l, r, out);
}